// Round 6
// baseline (44.172 us; speedup 1.0000x reference)
//
#include <hip/hip_runtime.h>
#include <math.h>

static constexpr int Bn = 64, Mn = 50, Cn = 4;
static constexpr int CORR_BLOCKS = 64;       // one per batch image
static constexpr int DENSE_BLOCKS = 1050;    // 2,688,000 float4 / 2560 per block
static constexpr int TOTAL_BLOCKS = CORR_BLOCKS + DENSE_BLOCKS;

// dense block d owns float4 range [d*2560, (d+1)*2560).
// wave w owns [d*2560 + w*640, +640) = 10 stages of 64 float4 (1KB).
// segment map in dense-block units (all boundaries exact):
//   c3 [0,640)  c4 [640,800)  c5 [800,840)  o3 [840,1000)  o4 [1000,1040)  o5 [1040,1050)
// ws layout (plain stores only, every slot rewritten every call):
//   [j*64 + b]   j=0..11, b=0..63 : corr partials
//   [768 + d]    d=0..1049        : per-dense-block base sums
static constexpr int BASE_OFF = 12 * 64;     // 768

#define LOG2E 1.4426950408889634f
#define LN2   0.6931471805599453f

__device__ __forceinline__ float frcp (float x){ return __builtin_amdgcn_rcpf(x); }
__device__ __forceinline__ float fexp2(float x){ return __builtin_amdgcn_exp2f(x); }
__device__ __forceinline__ float flog2(float x){ return __builtin_amdgcn_logf(x); }

__device__ __forceinline__ float focal0_4(float4 v) {
  float s = 0.f;
  const float* px = &v.x;
#pragma unroll
  for (int k = 0; k < 4; ++k) {
    float x = px[k];
    float e   = fexp2(-LOG2E * fabsf(x));           // exp(-|x|)
    float ope = 1.f + e;
    float u   = frcp(ope);                          // sigmoid(|x|)
    float sp  = fmaxf(x, 0.f) + LN2 * flog2(ope);   // softplus(x)
    float p   = (x >= 0.f) ? u : (1.f - u);         // sigmoid(x)
    s = fmaf(0.75f * p * p, sp, s);                 // focal(x, t=0)
  }
  return s;
}

__device__ __forceinline__ float obj0_4(float4 v) {
  float s = 0.f;
  const float* px = &v.x;
#pragma unroll
  for (int k = 0; k < 4; ++k) {
    float x = px[k];
    float e = fexp2(-LOG2E * fabsf(x));
    s += fmaxf(x, 0.f) + LN2 * flog2(1.f + e);      // softplus(x)
  }
  return s;
}

__device__ __forceinline__ float wave_reduce(float v) {
#pragma unroll
  for (int off = 32; off > 0; off >>= 1) v += __shfl_down(v, off, 64);
  return v;
}

// async 16B/lane global -> LDS (wave writes 1KB linearly at dst + lane*16)
__device__ __forceinline__ void load_lds_16(const void* g, void* l) {
  __builtin_amdgcn_global_load_lds(
      (const __attribute__((address_space(1))) void*)g,
      (__attribute__((address_space(3))) void*)l, 16, 0, 0);
}

__global__ __launch_bounds__(256) void main_kernel(
    const float* __restrict__ cls3, const float* __restrict__ reg3, const float* __restrict__ obj3,
    const float* __restrict__ cls4, const float* __restrict__ reg4, const float* __restrict__ obj4,
    const float* __restrict__ cls5, const float* __restrict__ reg5, const float* __restrict__ obj5,
    const float* __restrict__ boxes, const int* __restrict__ labels, const int* __restrict__ valid,
    float* __restrict__ ws) {
  __shared__ float4 lds[4][8][64];   // 4 waves x 8 ring slots x 1KB = 32KB

  if (blockIdx.x < CORR_BLOCKS) {
    // ---------------- sparse correction path: one block per batch image ----
    __shared__ int s_cell[Mn];
    __shared__ int s_lab[Mn];
    __shared__ float cacc[12];

    int b = blockIdx.x;
    int m = threadIdx.x;
    if (m < 12) cacc[m] = 0.f;

    float x1 = 0.f, y1 = 0.f, x2 = 0.f, y2 = 0.f;
    int lab = 0, val = 0;
    if (m < Mn) {
      const float* bp = boxes + ((size_t)b * Mn + m) * 4;
      x1 = bp[0]; y1 = bp[1]; x2 = bp[2]; y2 = bp[3];
      lab = labels[b * Mn + m];
      val = valid[b * Mn + m];
      s_lab[m] = lab;
    }

    for (int s = 0; s < 3; ++s) {
      const int W = (s == 0) ? 160 : ((s == 1) ? 80 : 40);
      const int H = W;
      const float stride = (s == 0) ? 8.f : ((s == 1) ? 16.f : 32.f);
      const float* clsP = (s == 0) ? cls3 : ((s == 1) ? cls4 : cls5);
      const float* regP = (s == 0) ? reg3 : ((s == 1) ? reg4 : reg5);
      const float* objP = (s == 0) ? obj3 : ((s == 1) ? obj4 : obj5);

      float cx = 0.f, cy = 0.f;
      int gx = 0, gy = 0, cell = -1;
      if (m < Mn && val > 0) {
        cx = (x1 + x2) * 0.5f / stride;
        cy = (y1 + y2) * 0.5f / stride;
        gx = min(max((int)cx, 0), W - 1);
        gy = min(max((int)cy, 0), H - 1);
        cell = gy * W + gx;
      }
      if (m < Mn) s_cell[m] = cell;
      __syncthreads();

      if (cell >= 0) {
        bool firstObj = true, lastReg = true, firstCls = true;
        for (int j = 0; j < Mn; ++j) {
          if (j == m) continue;
          if (s_cell[j] != cell) continue;
          if (j < m) {
            firstObj = false;
            if (s_lab[j] == lab) firstCls = false;
          } else {
            lastReg = false;   // a later valid box overwrites reg targets
          }
        }
        size_t plane = (size_t)H * W;
        size_t pix = (size_t)gy * W + gx;

        if (firstObj) {
          float x = objP[(size_t)b * plane + pix];
          float e = fexp2(-LOG2E * fabsf(x));
          float sp = fmaxf(x, 0.f) + LN2 * flog2(1.f + e);  // softplus(x)
          float corr = 0.5f * sp - 1.5f * x;                // 1.5*sp(-x) - sp(x)
          atomicAdd(&cacc[3 + s], corr);
          atomicAdd(&cacc[9 + s], 4.0f);                    // denom: 4 ch per cell
        }
        if (firstCls) {
          float x = clsP[((size_t)b * Cn + lab) * plane + pix];
          float e = fexp2(-LOG2E * fabsf(x));
          float ope = 1.f + e;
          float u = frcp(ope);
          float sp = fmaxf(x, 0.f) + LN2 * flog2(ope);
          float spn = sp - x;                               // softplus(-x)
          float p = (x >= 0.f) ? u : (1.f - u);
          float q = 1.f - p;
          float corr = 0.25f * q * q * spn - 0.75f * p * p * sp;
          atomicAdd(&cacc[0 + s], corr);
        }
        if (lastReg) {
          float w = fmaxf(x2 - x1, 1.f), h = fmaxf(y2 - y1, 1.f);
          float inv_s = 1.f / stride;
          float t0 = cx - (float)gx, t1 = cy - (float)gy;
          float t2 = LN2 * flog2(w * inv_s), t3 = LN2 * flog2(h * inv_s);
          const float* rp = regP + (size_t)b * 4 * plane + pix;
          float sum = 0.f, d, a;
          d = rp[0]         - t0; a = fabsf(d); sum += (a < 1.f) ? 0.5f * d * d : a - 0.5f;
          d = rp[plane]     - t1; a = fabsf(d); sum += (a < 1.f) ? 0.5f * d * d : a - 0.5f;
          d = rp[2 * plane] - t2; a = fabsf(d); sum += (a < 1.f) ? 0.5f * d * d : a - 0.5f;
          d = rp[3 * plane] - t3; a = fabsf(d); sum += (a < 1.f) ? 0.5f * d * d : a - 0.5f;
          atomicAdd(&cacc[6 + s], sum);
        }
      }
      __syncthreads();
    }

    if (m < 12) ws[m * 64 + b] = cacc[m];   // private slot, plain store
  } else {
    // ------- dense base path: per-wave 10-stage global->LDS ring pipeline ---
    __shared__ float sdata[4];
    const int d = (int)blockIdx.x - CORR_BLOCKS;

    const float4* src;
    bool isCls;
    if (d < 640)       { src = (const float4*)cls3 + (size_t)d * 2560;          isCls = true;  }
    else if (d < 800)  { src = (const float4*)cls4 + (size_t)(d - 640) * 2560;  isCls = true;  }
    else if (d < 840)  { src = (const float4*)cls5 + (size_t)(d - 800) * 2560;  isCls = true;  }
    else if (d < 1000) { src = (const float4*)obj3 + (size_t)(d - 840) * 2560;  isCls = false; }
    else if (d < 1040) { src = (const float4*)obj4 + (size_t)(d - 1000) * 2560; isCls = false; }
    else               { src = (const float4*)obj5 + (size_t)(d - 1040) * 2560; isCls = false; }

    const int lane = threadIdx.x & 63;
    const int wid = threadIdx.x >> 6;
    const float4* wsrc = src + wid * 640 + lane;   // this lane's stage-0 element

    // prologue: 4 stages in flight
#pragma unroll
    for (int t = 0; t < 4; ++t)
      load_lds_16(wsrc + t * 64, &lds[wid][t][0]);

    float s = 0.f;
#pragma unroll
    for (int t = 0; t < 6; ++t) {
      asm volatile("s_waitcnt vmcnt(3)" ::: "memory");   // stage t landed
      __builtin_amdgcn_sched_barrier(0);
      float4 v = lds[wid][t][lane];
      s += isCls ? focal0_4(v) : obj0_4(v);
      load_lds_16(wsrc + (t + 4) * 64, &lds[wid][(t + 4) & 7][0]);
    }
    asm volatile("s_waitcnt vmcnt(0)" ::: "memory");     // stages 6..9 landed
    __builtin_amdgcn_sched_barrier(0);
#pragma unroll
    for (int t = 6; t < 10; ++t) {
      float4 v = lds[wid][t & 7][lane];
      s += isCls ? focal0_4(v) : obj0_4(v);
    }

    s = wave_reduce(s);
    if (lane == 0) sdata[wid] = s;
    __syncthreads();
    if (threadIdx.x == 0)
      ws[BASE_OFF + d] = sdata[0] + sdata[1] + sdata[2] + sdata[3];
  }
}

__global__ __launch_bounds__(256) void finalize_kernel(
    const float* __restrict__ ws, float* __restrict__ out) {
  __shared__ float sdata[6][4];
  __shared__ float res[18];
  const int t = threadIdx.x;
  const int lane = t & 63;
  const int wid = t >> 6;

  // reduce the 1050 per-block base sums, classified by dense-block index
  float a0 = 0.f, a1 = 0.f, a2 = 0.f, a3 = 0.f, a4 = 0.f, a5 = 0.f;
  for (int i = t; i < DENSE_BLOCKS; i += 256) {
    float v = ws[BASE_OFF + i];
    if (i < 640)       a0 += v;
    else if (i < 800)  a1 += v;
    else if (i < 840)  a2 += v;
    else if (i < 1000) a3 += v;
    else if (i < 1040) a4 += v;
    else               a5 += v;
  }
  float acc[6] = {a0, a1, a2, a3, a4, a5};
#pragma unroll
  for (int k = 0; k < 6; ++k) {
    float s = wave_reduce(acc[k]);
    if (lane == 0) sdata[k][wid] = s;
  }
  __syncthreads();
  if (t < 6) res[t] = sdata[t][0] + sdata[t][1] + sdata[t][2] + sdata[t][3];

  // reduce the 12 corr rows (64 partials each) on wave 0
  if (wid == 0) {
#pragma unroll
    for (int j = 0; j < 12; ++j) {
      float v = ws[j * 64 + lane];
      v = wave_reduce(v);
      if (lane == 0) res[6 + j] = v;
    }
  }
  __syncthreads();

  if (t == 0) {
    const float cls_cnt[3] = {6553600.f, 1638400.f, 409600.f};
    const float obj_cnt[3] = {1638400.f, 409600.f, 102400.f};
    float tc = 0.f, to = 0.f, tr = 0.f;
#pragma unroll
    for (int s = 0; s < 3; ++s) {
      tc += (res[s] + res[6 + s]) / cls_cnt[s];        // base + cls corr
      to += (res[3 + s] + res[9 + s]) / obj_cnt[s];    // base + obj corr
      float den = res[15 + s];
      if (den > 0.f) tr += res[12 + s] / fmaxf(den, 1.f);
    }
    float total = 2.5f * tc + 5.0f * tr + 0.5f * to;
    out[0] = total; out[1] = tc; out[2] = tr; out[3] = to;
  }
}

extern "C" void kernel_launch(void* const* d_in, const int* in_sizes, int n_in,
                              void* d_out, int out_size, void* d_ws, size_t ws_size,
                              hipStream_t stream) {
  const float* cls3 = (const float*)d_in[0];
  const float* reg3 = (const float*)d_in[1];
  const float* obj3 = (const float*)d_in[2];
  const float* cls4 = (const float*)d_in[3];
  const float* reg4 = (const float*)d_in[4];
  const float* obj4 = (const float*)d_in[5];
  const float* cls5 = (const float*)d_in[6];
  const float* reg5 = (const float*)d_in[7];
  const float* obj5 = (const float*)d_in[8];
  const float* boxes = (const float*)d_in[9];
  const int* labels = (const int*)d_in[10];
  const int* valid = (const int*)d_in[11];
  float* ws = (float*)d_ws;
  float* out = (float*)d_out;

  main_kernel<<<TOTAL_BLOCKS, 256, 0, stream>>>(
      cls3, reg3, obj3, cls4, reg4, obj4, cls5, reg5, obj5,
      boxes, labels, valid, ws);

  finalize_kernel<<<1, 256, 0, stream>>>(ws, out);
}

// Round 7
// 42.572 us; speedup vs baseline: 1.0376x; 1.0376x over previous
//
#include <hip/hip_runtime.h>
#include <math.h>

static constexpr int Bn = 64, Mn = 50, Cn = 4;
static constexpr int CORR_BLOCKS = 64;      // one per batch image
static constexpr int DENSE_BLOCKS = 420;    // 2,688,000 float4 / 6400 per block
static constexpr int TOTAL_BLOCKS = CORR_BLOCKS + DENSE_BLOCKS;   // 484

// dense block d owns float4 range [d*6400, (d+1)*6400); 25 float4 per thread.
// segment map (block-uniform, boundaries all divide 6400):
//   c3 [0,256)  c4 [256,320)  c5 [320,336)  o3 [336,400)  o4 [400,416)  o5 [416,420)
// ws layout (plain stores only, every slot rewritten every call):
//   [j*64 + b]   j=0..11, b=0..63 : corr partials
//   [768 + d]    d=0..419         : per-dense-block base sums
static constexpr int BASE_OFF = 12 * 64;    // 768

#define LOG2E 1.4426950408889634f
#define LN2   0.6931471805599453f

__device__ __forceinline__ float frcp (float x){ return __builtin_amdgcn_rcpf(x); }
__device__ __forceinline__ float fexp2(float x){ return __builtin_amdgcn_exp2f(x); }
__device__ __forceinline__ float flog2(float x){ return __builtin_amdgcn_logf(x); }

// unified focal(x,0)/softplus(x): cf=1 -> 0.75*sigmoid(x)^2*softplus(x); cf=0 -> softplus(x)
__device__ __forceinline__ float proc4(float4 v, float cf) {
  float s = 0.f;
  const float* px = &v.x;
#pragma unroll
  for (int k = 0; k < 4; ++k) {
    float x = px[k];
    float e   = fexp2(-LOG2E * fabsf(x));           // exp(-|x|)
    float ope = 1.f + e;
    float u   = frcp(ope);                          // sigmoid(|x|)
    float sp  = fmaxf(x, 0.f) + LN2 * flog2(ope);   // softplus(x)
    float p   = (x >= 0.f) ? u : (1.f - u);         // sigmoid(x)
    float w   = fmaf(cf, fmaf(0.75f, p * p, -1.f), 1.f);  // cf?0.75p^2:1
    s = fmaf(sp, w, s);
  }
  return s;
}

__device__ __forceinline__ float wave_reduce(float v) {
#pragma unroll
  for (int off = 32; off > 0; off >>= 1) v += __shfl_down(v, off, 64);
  return v;
}

__global__ __launch_bounds__(256) void main_kernel(
    const float* __restrict__ cls3, const float* __restrict__ reg3, const float* __restrict__ obj3,
    const float* __restrict__ cls4, const float* __restrict__ reg4, const float* __restrict__ obj4,
    const float* __restrict__ cls5, const float* __restrict__ reg5, const float* __restrict__ obj5,
    const float* __restrict__ boxes, const int* __restrict__ labels, const int* __restrict__ valid,
    float* __restrict__ ws) {
  if (blockIdx.x < CORR_BLOCKS) {
    // ---------------- sparse correction path: one block per batch image ----
    __shared__ int s_cell[Mn];
    __shared__ int s_lab[Mn];
    __shared__ float cacc[12];

    int b = blockIdx.x;
    int m = threadIdx.x;
    if (m < 12) cacc[m] = 0.f;

    float x1 = 0.f, y1 = 0.f, x2 = 0.f, y2 = 0.f;
    int lab = 0, val = 0;
    if (m < Mn) {
      const float* bp = boxes + ((size_t)b * Mn + m) * 4;
      x1 = bp[0]; y1 = bp[1]; x2 = bp[2]; y2 = bp[3];
      lab = labels[b * Mn + m];
      val = valid[b * Mn + m];
      s_lab[m] = lab;
    }

    for (int s = 0; s < 3; ++s) {
      const int W = (s == 0) ? 160 : ((s == 1) ? 80 : 40);
      const int H = W;
      const float stride = (s == 0) ? 8.f : ((s == 1) ? 16.f : 32.f);
      const float* clsP = (s == 0) ? cls3 : ((s == 1) ? cls4 : cls5);
      const float* regP = (s == 0) ? reg3 : ((s == 1) ? reg4 : reg5);
      const float* objP = (s == 0) ? obj3 : ((s == 1) ? obj4 : obj5);

      float cx = 0.f, cy = 0.f;
      int gx = 0, gy = 0, cell = -1;
      if (m < Mn && val > 0) {
        cx = (x1 + x2) * 0.5f / stride;
        cy = (y1 + y2) * 0.5f / stride;
        gx = min(max((int)cx, 0), W - 1);
        gy = min(max((int)cy, 0), H - 1);
        cell = gy * W + gx;
      }
      if (m < Mn) s_cell[m] = cell;
      __syncthreads();

      if (cell >= 0) {
        bool firstObj = true, lastReg = true, firstCls = true;
        for (int j = 0; j < Mn; ++j) {
          if (j == m) continue;
          if (s_cell[j] != cell) continue;
          if (j < m) {
            firstObj = false;
            if (s_lab[j] == lab) firstCls = false;
          } else {
            lastReg = false;   // a later valid box overwrites reg targets
          }
        }
        size_t plane = (size_t)H * W;
        size_t pix = (size_t)gy * W + gx;

        if (firstObj) {
          float x = objP[(size_t)b * plane + pix];
          float e = fexp2(-LOG2E * fabsf(x));
          float sp = fmaxf(x, 0.f) + LN2 * flog2(1.f + e);  // softplus(x)
          float corr = 0.5f * sp - 1.5f * x;                // 1.5*sp(-x) - sp(x)
          atomicAdd(&cacc[3 + s], corr);
          atomicAdd(&cacc[9 + s], 4.0f);                    // denom: 4 ch per cell
        }
        if (firstCls) {
          float x = clsP[((size_t)b * Cn + lab) * plane + pix];
          float e = fexp2(-LOG2E * fabsf(x));
          float ope = 1.f + e;
          float u = frcp(ope);
          float sp = fmaxf(x, 0.f) + LN2 * flog2(ope);
          float spn = sp - x;                               // softplus(-x)
          float p = (x >= 0.f) ? u : (1.f - u);
          float q = 1.f - p;
          float corr = 0.25f * q * q * spn - 0.75f * p * p * sp;
          atomicAdd(&cacc[0 + s], corr);
        }
        if (lastReg) {
          float w = fmaxf(x2 - x1, 1.f), h = fmaxf(y2 - y1, 1.f);
          float inv_s = 1.f / stride;
          float t0 = cx - (float)gx, t1 = cy - (float)gy;
          float t2 = LN2 * flog2(w * inv_s), t3 = LN2 * flog2(h * inv_s);
          const float* rp = regP + (size_t)b * 4 * plane + pix;
          float sum = 0.f, d, a;
          d = rp[0]         - t0; a = fabsf(d); sum += (a < 1.f) ? 0.5f * d * d : a - 0.5f;
          d = rp[plane]     - t1; a = fabsf(d); sum += (a < 1.f) ? 0.5f * d * d : a - 0.5f;
          d = rp[2 * plane] - t2; a = fabsf(d); sum += (a < 1.f) ? 0.5f * d * d : a - 0.5f;
          d = rp[3 * plane] - t3; a = fabsf(d); sum += (a < 1.f) ? 0.5f * d * d : a - 0.5f;
          atomicAdd(&cacc[6 + s], sum);
        }
      }
      __syncthreads();
    }

    if (m < 12) ws[m * 64 + b] = cacc[m];   // private slot, plain store
  } else {
    // ------ dense base path: asm 8-deep global_load_dwordx4 pipeline -------
    __shared__ float sdata[4];
    const int d = (int)blockIdx.x - CORR_BLOCKS;

    const float4* src;
    float cf;
    if (d < 256)      { src = (const float4*)cls3 + (size_t)d * 6400;         cf = 1.f; }
    else if (d < 320) { src = (const float4*)cls4 + (size_t)(d - 256) * 6400; cf = 1.f; }
    else if (d < 336) { src = (const float4*)cls5 + (size_t)(d - 320) * 6400; cf = 1.f; }
    else if (d < 400) { src = (const float4*)obj3 + (size_t)(d - 336) * 6400; cf = 0.f; }
    else if (d < 416) { src = (const float4*)obj4 + (size_t)(d - 400) * 6400; cf = 0.f; }
    else              { src = (const float4*)obj5 + (size_t)(d - 416) * 6400; cf = 0.f; }

    unsigned long long base = (unsigned long long)src;
    unsigned off = threadIdx.x * 16u;   // byte voffset; +0x1000 per load (256 float4)
    float4 v0, v1, v2, v3, v4, v5, v6, v7;
    float s = 0.f;

// issue one 16B load at s[base]+off, then post-increment off by 4096
#define ISSUE(vk) asm volatile( \
      "global_load_dwordx4 %0, %1, %2\n\t" \
      "v_add_u32 %1, 0x1000, %1" \
      : "=&v"(vk), "+v"(off) : "s"(base) : "memory")
#define WAITC(n) do { asm volatile("s_waitcnt vmcnt(" #n ")" ::: "memory"); \
      __builtin_amdgcn_sched_barrier(0); } while (0)

    // prologue: 8 loads in flight
    ISSUE(v0); ISSUE(v1); ISSUE(v2); ISSUE(v3);
    ISSUE(v4); ISSUE(v5); ISSUE(v6); ISSUE(v7);

    // steady: consume L0..L16, issue L8..L24 (always 8 outstanding)
    WAITC(7); s += proc4(v0, cf); ISSUE(v0);
    WAITC(7); s += proc4(v1, cf); ISSUE(v1);
    WAITC(7); s += proc4(v2, cf); ISSUE(v2);
    WAITC(7); s += proc4(v3, cf); ISSUE(v3);
    WAITC(7); s += proc4(v4, cf); ISSUE(v4);
    WAITC(7); s += proc4(v5, cf); ISSUE(v5);
    WAITC(7); s += proc4(v6, cf); ISSUE(v6);
    WAITC(7); s += proc4(v7, cf); ISSUE(v7);
    WAITC(7); s += proc4(v0, cf); ISSUE(v0);
    WAITC(7); s += proc4(v1, cf); ISSUE(v1);
    WAITC(7); s += proc4(v2, cf); ISSUE(v2);
    WAITC(7); s += proc4(v3, cf); ISSUE(v3);
    WAITC(7); s += proc4(v4, cf); ISSUE(v4);
    WAITC(7); s += proc4(v5, cf); ISSUE(v5);
    WAITC(7); s += proc4(v6, cf); ISSUE(v6);
    WAITC(7); s += proc4(v7, cf); ISSUE(v7);
    WAITC(7); s += proc4(v0, cf); ISSUE(v0);   // consume L16, issue L24

    // drain: L17..L24 live in slots 1..7,0
    WAITC(7); s += proc4(v1, cf);
    WAITC(6); s += proc4(v2, cf);
    WAITC(5); s += proc4(v3, cf);
    WAITC(4); s += proc4(v4, cf);
    WAITC(3); s += proc4(v5, cf);
    WAITC(2); s += proc4(v6, cf);
    WAITC(1); s += proc4(v7, cf);
    WAITC(0); s += proc4(v0, cf);

#undef ISSUE
#undef WAITC

    s = wave_reduce(s);
    const int lane = threadIdx.x & 63;
    const int wid = threadIdx.x >> 6;
    if (lane == 0) sdata[wid] = s;
    __syncthreads();
    if (threadIdx.x == 0)
      ws[BASE_OFF + d] = sdata[0] + sdata[1] + sdata[2] + sdata[3];
  }
}

__global__ __launch_bounds__(256) void finalize_kernel(
    const float* __restrict__ ws, float* __restrict__ out) {
  __shared__ float sdata[6][4];
  __shared__ float res[18];
  const int t = threadIdx.x;
  const int lane = t & 63;
  const int wid = t >> 6;

  // reduce the 420 per-block base sums, classified by dense-block index
  float a0 = 0.f, a1 = 0.f, a2 = 0.f, a3 = 0.f, a4 = 0.f, a5 = 0.f;
  for (int i = t; i < DENSE_BLOCKS; i += 256) {
    float v = ws[BASE_OFF + i];
    if (i < 256)      a0 += v;
    else if (i < 320) a1 += v;
    else if (i < 336) a2 += v;
    else if (i < 400) a3 += v;
    else if (i < 416) a4 += v;
    else              a5 += v;
  }
  float acc[6] = {a0, a1, a2, a3, a4, a5};
#pragma unroll
  for (int k = 0; k < 6; ++k) {
    float s = wave_reduce(acc[k]);
    if (lane == 0) sdata[k][wid] = s;
  }
  __syncthreads();
  if (t < 6) res[t] = sdata[t][0] + sdata[t][1] + sdata[t][2] + sdata[t][3];

  // reduce the 12 corr rows (64 partials each) on wave 0
  if (wid == 0) {
#pragma unroll
    for (int j = 0; j < 12; ++j) {
      float v = ws[j * 64 + lane];
      v = wave_reduce(v);
      if (lane == 0) res[6 + j] = v;
    }
  }
  __syncthreads();

  if (t == 0) {
    const float cls_cnt[3] = {6553600.f, 1638400.f, 409600.f};
    const float obj_cnt[3] = {1638400.f, 409600.f, 102400.f};
    float tc = 0.f, to = 0.f, tr = 0.f;
#pragma unroll
    for (int s = 0; s < 3; ++s) {
      tc += (res[s] + res[6 + s]) / cls_cnt[s];        // base + cls corr
      to += (res[3 + s] + res[9 + s]) / obj_cnt[s];    // base + obj corr
      float den = res[15 + s];
      if (den > 0.f) tr += res[12 + s] / fmaxf(den, 1.f);
    }
    float total = 2.5f * tc + 5.0f * tr + 0.5f * to;
    out[0] = total; out[1] = tc; out[2] = tr; out[3] = to;
  }
}

extern "C" void kernel_launch(void* const* d_in, const int* in_sizes, int n_in,
                              void* d_out, int out_size, void* d_ws, size_t ws_size,
                              hipStream_t stream) {
  const float* cls3 = (const float*)d_in[0];
  const float* reg3 = (const float*)d_in[1];
  const float* obj3 = (const float*)d_in[2];
  const float* cls4 = (const float*)d_in[3];
  const float* reg4 = (const float*)d_in[4];
  const float* obj4 = (const float*)d_in[5];
  const float* cls5 = (const float*)d_in[6];
  const float* reg5 = (const float*)d_in[7];
  const float* obj5 = (const float*)d_in[8];
  const float* boxes = (const float*)d_in[9];
  const int* labels = (const int*)d_in[10];
  const int* valid = (const int*)d_in[11];
  float* ws = (float*)d_ws;
  float* out = (float*)d_out;

  main_kernel<<<TOTAL_BLOCKS, 256, 0, stream>>>(
      cls3, reg3, obj3, cls4, reg4, obj4, cls5, reg5, obj5,
      boxes, labels, valid, ws);

  finalize_kernel<<<1, 256, 0, stream>>>(ws, out);
}

// Round 8
// 22.945 us; speedup vs baseline: 1.9251x; 1.8554x over previous
//
#include <hip/hip_runtime.h>
#include <math.h>

static constexpr int Bn = 64, Mn = 50, Cn = 4;
static constexpr int CORR_BLOCKS = 64;       // one per batch image
static constexpr int DENSE_BLOCKS = 512;     // segment-pure, 1024 threads each
static constexpr int TOTAL_BLOCKS = CORR_BLOCKS + DENSE_BLOCKS;  // 576

// dense tiles: 1024 float4 per tile, 1 float4/thread.
// segment tiles: c3 1600, c4 400, c5 100, o3 400, o4 100, o5 25  (total 2625)
// dense block ranges (d = blockIdx.x - 64):
//   c3 [0,311)  c4 [311,389)  c5 [389,409)  o3 [409,487)  o4 [487,507)  o5 [507,512)
// block with local index bk of nB grid-strides tiles bk, bk+nB, ... < nT  (5-6 tiles)
// ws layout (plain stores only, every slot rewritten every call):
//   [j*64 + b]   j=0..11, b=0..63 : corr partials
//                j 0..2 cls corr, 3..5 obj corr, 6..8 reg sum, 9..11 denom
//   [768 + d]    d=0..511         : per-dense-block sums (segment-pure)
static constexpr int BASE_OFF = 12 * 64;     // 768

#define LOG2E 1.4426950408889634f
#define LN2   0.6931471805599453f

__device__ __forceinline__ float frcp (float x){ return __builtin_amdgcn_rcpf(x); }
__device__ __forceinline__ float fexp2(float x){ return __builtin_amdgcn_exp2f(x); }
__device__ __forceinline__ float flog2(float x){ return __builtin_amdgcn_logf(x); }

// cf=1 -> 0.75*sigmoid(x)^2*softplus(x) (focal t=0); cf=0 -> softplus(x) (obj t=0)
__device__ __forceinline__ float proc4(float4 v, float cf) {
  float s = 0.f;
  const float* px = &v.x;
#pragma unroll
  for (int k = 0; k < 4; ++k) {
    float x = px[k];
    float e   = fexp2(-LOG2E * fabsf(x));           // exp(-|x|)
    float ope = 1.f + e;
    float u   = frcp(ope);                          // sigmoid(|x|)
    float sp  = fmaxf(x, 0.f) + LN2 * flog2(ope);   // softplus(x)
    float p   = (x >= 0.f) ? u : (1.f - u);         // sigmoid(x)
    float w   = fmaf(cf, fmaf(0.75f, p * p, -1.f), 1.f);  // cf?0.75p^2:1
    s = fmaf(sp, w, s);
  }
  return s;
}

__device__ __forceinline__ float wave_reduce(float v) {
#pragma unroll
  for (int off = 32; off > 0; off >>= 1) v += __shfl_down(v, off, 64);
  return v;
}

__global__ __launch_bounds__(1024, 8) void main_kernel(
    const float* __restrict__ cls3, const float* __restrict__ reg3, const float* __restrict__ obj3,
    const float* __restrict__ cls4, const float* __restrict__ reg4, const float* __restrict__ obj4,
    const float* __restrict__ cls5, const float* __restrict__ reg5, const float* __restrict__ obj5,
    const float* __restrict__ boxes, const int* __restrict__ labels, const int* __restrict__ valid,
    float* __restrict__ ws) {
  if (blockIdx.x < CORR_BLOCKS) {
    // ------- sparse correction path: all 3 scales concurrent, 150 lanes ----
    __shared__ int s_cell[3][Mn];
    __shared__ int s_lab[Mn];
    __shared__ float cacc[12];

    const int b = blockIdx.x;
    const int tid = threadIdx.x;
    if (tid < 12) cacc[tid] = 0.f;

    const int s = tid / Mn;      // scale 0..2 for tid<150
    const int m = tid - s * Mn;  // box index

    float x1 = 0.f, y1 = 0.f, x2 = 0.f, y2 = 0.f;
    int lab = 0, val = 0;
    float cx = 0.f, cy = 0.f, strf = 8.f;
    int gx = 0, gy = 0, cell = -1, W = 160;

    if (tid < 150) {
      const float* bp = boxes + ((size_t)b * Mn + m) * 4;
      x1 = bp[0]; y1 = bp[1]; x2 = bp[2]; y2 = bp[3];
      lab = labels[b * Mn + m];
      val = valid[b * Mn + m];
      if (s == 0) s_lab[m] = lab;   // same for all scales

      W = 160 >> s;
      strf = (float)(8 << s);
      if (val > 0) {
        float inv_s = frcp(strf);
        cx = (x1 + x2) * 0.5f * inv_s;
        cy = (y1 + y2) * 0.5f * inv_s;
        gx = min(max((int)cx, 0), W - 1);
        gy = min(max((int)cy, 0), W - 1);
        cell = gy * W + gx;
      }
      s_cell[s][m] = cell;
    }
    __syncthreads();

    if (tid < 150 && cell >= 0) {
      const float* clsP = (s == 0) ? cls3 : ((s == 1) ? cls4 : cls5);
      const float* regP = (s == 0) ? reg3 : ((s == 1) ? reg4 : reg5);
      const float* objP = (s == 0) ? obj3 : ((s == 1) ? obj4 : obj5);

      bool firstObj = true, lastReg = true, firstCls = true;
      for (int j = 0; j < Mn; ++j) {
        if (j == m) continue;
        if (s_cell[s][j] != cell) continue;
        if (j < m) {
          firstObj = false;
          if (s_lab[j] == lab) firstCls = false;
        } else {
          lastReg = false;   // a later valid box overwrites reg targets
        }
      }
      size_t plane = (size_t)W * W;
      size_t pix = (size_t)gy * W + gx;

      if (firstObj) {
        float x = objP[(size_t)b * plane + pix];
        float e = fexp2(-LOG2E * fabsf(x));
        float sp = fmaxf(x, 0.f) + LN2 * flog2(1.f + e);  // softplus(x)
        float corr = 0.5f * sp - 1.5f * x;                // 1.5*sp(-x) - sp(x)
        atomicAdd(&cacc[3 + s], corr);
        atomicAdd(&cacc[9 + s], 4.0f);                    // denom: 4 ch per cell
      }
      if (firstCls) {
        float x = clsP[((size_t)b * Cn + lab) * plane + pix];
        float e = fexp2(-LOG2E * fabsf(x));
        float ope = 1.f + e;
        float u = frcp(ope);
        float sp = fmaxf(x, 0.f) + LN2 * flog2(ope);
        float spn = sp - x;                               // softplus(-x)
        float p = (x >= 0.f) ? u : (1.f - u);
        float q = 1.f - p;
        float corr = 0.25f * q * q * spn - 0.75f * p * p * sp;
        atomicAdd(&cacc[0 + s], corr);
      }
      if (lastReg) {
        float w = fmaxf(x2 - x1, 1.f), h = fmaxf(y2 - y1, 1.f);
        float inv_s = frcp(strf);
        float t0 = cx - (float)gx, t1 = cy - (float)gy;
        float t2 = LN2 * flog2(w * inv_s), t3 = LN2 * flog2(h * inv_s);
        const float* rp = regP + (size_t)b * 4 * plane + pix;
        float sum = 0.f, d, a;
        d = rp[0]         - t0; a = fabsf(d); sum += (a < 1.f) ? 0.5f * d * d : a - 0.5f;
        d = rp[plane]     - t1; a = fabsf(d); sum += (a < 1.f) ? 0.5f * d * d : a - 0.5f;
        d = rp[2 * plane] - t2; a = fabsf(d); sum += (a < 1.f) ? 0.5f * d * d : a - 0.5f;
        d = rp[3 * plane] - t3; a = fabsf(d); sum += (a < 1.f) ? 0.5f * d * d : a - 0.5f;
        atomicAdd(&cacc[6 + s], sum);
      }
    }
    __syncthreads();
    if (tid < 12) ws[tid * 64 + b] = cacc[tid];   // private slot, plain store
  } else {
    // ------- dense base path: segment-pure block, grid-stride over tiles ---
    __shared__ float sdata[16];
    const int d = (int)blockIdx.x - CORR_BLOCKS;
    const int tid = threadIdx.x;

    const float4* sb; int bk, nB, nT; float cf;
    if (d < 311)      { sb = (const float4*)cls3; bk = d;       nB = 311; nT = 1600; cf = 1.f; }
    else if (d < 389) { sb = (const float4*)cls4; bk = d - 311; nB = 78;  nT = 400;  cf = 1.f; }
    else if (d < 409) { sb = (const float4*)cls5; bk = d - 389; nB = 20;  nT = 100;  cf = 1.f; }
    else if (d < 487) { sb = (const float4*)obj3; bk = d - 409; nB = 78;  nT = 400;  cf = 0.f; }
    else if (d < 507) { sb = (const float4*)obj4; bk = d - 487; nB = 20;  nT = 100;  cf = 0.f; }
    else              { sb = (const float4*)obj5; bk = d - 507; nB = 5;   nT = 25;   cf = 0.f; }

    float s = 0.f;
    int t = bk;
    float4 v = sb[(size_t)t * 1024 + tid];      // first tile in flight
    for (t += nB; t < nT; t += nB) {
      float4 vn = sb[(size_t)t * 1024 + tid];   // prefetch next tile
      s += proc4(v, cf);
      v = vn;
    }
    s += proc4(v, cf);

    s = wave_reduce(s);
    const int lane = tid & 63;
    const int wid = tid >> 6;
    if (lane == 0) sdata[wid] = s;
    __syncthreads();
    if (tid == 0) {
      float r = 0.f;
#pragma unroll
      for (int i = 0; i < 16; ++i) r += sdata[i];
      ws[BASE_OFF + d] = r;
    }
  }
}

__global__ __launch_bounds__(256) void finalize_kernel(
    const float* __restrict__ ws, float* __restrict__ out) {
  __shared__ float sdata[6][4];
  __shared__ float res[18];
  const int t = threadIdx.x;
  const int lane = t & 63;
  const int wid = t >> 6;

  // reduce the 512 per-block dense sums, classified by dense-block index
  float a0 = 0.f, a1 = 0.f, a2 = 0.f, a3 = 0.f, a4 = 0.f, a5 = 0.f;
  for (int i = t; i < DENSE_BLOCKS; i += 256) {
    float v = ws[BASE_OFF + i];
    if (i < 311)      a0 += v;
    else if (i < 389) a1 += v;
    else if (i < 409) a2 += v;
    else if (i < 487) a3 += v;
    else if (i < 507) a4 += v;
    else              a5 += v;
  }
  float acc[6] = {a0, a1, a2, a3, a4, a5};
#pragma unroll
  for (int k = 0; k < 6; ++k) {
    float s = wave_reduce(acc[k]);
    if (lane == 0) sdata[k][wid] = s;
  }
  __syncthreads();
  if (t < 6) res[t] = sdata[t][0] + sdata[t][1] + sdata[t][2] + sdata[t][3];

  // reduce the 12 corr rows (64 partials each) on wave 0
  if (wid == 0) {
#pragma unroll
    for (int j = 0; j < 12; ++j) {
      float v = ws[j * 64 + lane];
      v = wave_reduce(v);
      if (lane == 0) res[6 + j] = v;
    }
  }
  __syncthreads();

  if (t == 0) {
    const float cls_cnt[3] = {6553600.f, 1638400.f, 409600.f};
    const float obj_cnt[3] = {1638400.f, 409600.f, 102400.f};
    float tc = 0.f, to = 0.f, tr = 0.f;
#pragma unroll
    for (int s = 0; s < 3; ++s) {
      tc += (res[s] + res[6 + s]) / cls_cnt[s];        // base + cls corr
      to += (res[3 + s] + res[9 + s]) / obj_cnt[s];    // base + obj corr
      float den = res[15 + s];
      if (den > 0.f) tr += res[12 + s] / fmaxf(den, 1.f);
    }
    float total = 2.5f * tc + 5.0f * tr + 0.5f * to;
    out[0] = total; out[1] = tc; out[2] = tr; out[3] = to;
  }
}

extern "C" void kernel_launch(void* const* d_in, const int* in_sizes, int n_in,
                              void* d_out, int out_size, void* d_ws, size_t ws_size,
                              hipStream_t stream) {
  const float* cls3 = (const float*)d_in[0];
  const float* reg3 = (const float*)d_in[1];
  const float* obj3 = (const float*)d_in[2];
  const float* cls4 = (const float*)d_in[3];
  const float* reg4 = (const float*)d_in[4];
  const float* obj4 = (const float*)d_in[5];
  const float* cls5 = (const float*)d_in[6];
  const float* reg5 = (const float*)d_in[7];
  const float* obj5 = (const float*)d_in[8];
  const float* boxes = (const float*)d_in[9];
  const int* labels = (const int*)d_in[10];
  const int* valid = (const int*)d_in[11];
  float* ws = (float*)d_ws;
  float* out = (float*)d_out;

  main_kernel<<<TOTAL_BLOCKS, 1024, 0, stream>>>(
      cls3, reg3, obj3, cls4, reg4, obj4, cls5, reg5, obj5,
      boxes, labels, valid, ws);

  finalize_kernel<<<1, 256, 0, stream>>>(ws, out);
}